// Round 1
// baseline (34307.755 us; speedup 1.0000x reference)
//
#include <hip/hip_runtime.h>

// quadjetResNetBlock: N=65536 rows, NQ=256 channels, 3 groups, 3 conv layers.
// Decomposition: per group g, per layer l:
//   out[n,o] = sum_c x[n,c,2g]*W[o,c,0] + x[n,c,2g+1]*W[o,c,1] + q[n,c,g]*W[o,c,2] + b[o]
// relu between layers; final: relu(out3 + q_orig).
// Fully fused, fp32 vector math (no fp32 MFMA on CDNA4). One kernel, no workspace.

#define NROWS 65536
#define CH    256   // NQ
#define TM    16    // rows per block
#define PAD   20    // LDS row-stride in floats (16B-aligned: 20*4=80; breaks pow2 banks)

__global__ __launch_bounds__(256, 2)
void qjrb_fused(const float* __restrict__ x, const float* __restrict__ q,
                const float* __restrict__ W1, const float* __restrict__ b1,
                const float* __restrict__ W2, const float* __restrict__ b2,
                const float* __restrict__ W3, const float* __restrict__ b3,
                float* __restrict__ out)
{
    // v-tiles, layout [c][r] so compute reads are row-vectors (broadcast across lanes)
    __shared__ float vx0[CH * PAD];
    __shared__ float vx1[CH * PAD];
    __shared__ float vq [CH * PAD];

    const int tid  = threadIdx.x;
    const int n0   = blockIdx.x * TM;
    const int tcol = tid & 31;   // 32 col-groups
    const int trow = tid >> 5;   // 8 row-groups
    const int r0   = trow * 2;   // 2 rows/thread
    const int o0   = tcol * 8;   // 8 out-channels/thread

    for (int g = 0; g < 3; ++g) {
        __syncthreads();  // previous pass finished reading LDS
        // ---- stage x cols (2g,2g+1) and q col g into LDS, transposed to [c][r]
        {
            const int c = tid;  // one channel per thread
            #pragma unroll
            for (int r = 0; r < TM; ++r) {
                const int base = (n0 + r) * CH + c;
                const float2 xx = *reinterpret_cast<const float2*>(x + base * 6 + 2 * g);
                vx0[c * PAD + r] = xx.x;
                vx1[c * PAD + r] = xx.y;
                vq [c * PAD + r] = q[base * 3 + g];
            }
        }
        __syncthreads();

        float acc[2][8];
        for (int l = 0; l < 3; ++l) {
            const float* __restrict__ W = (l == 0) ? W1 : (l == 1) ? W2 : W3;
            const float* __restrict__ b = (l == 0) ? b1 : (l == 1) ? b2 : b3;

            #pragma unroll
            for (int j = 0; j < 8; ++j) {
                const float bv = b[o0 + j];
                acc[0][j] = bv;
                acc[1][j] = bv;
            }

            for (int c = 0; c < CH; ++c) {
                const float2 a0 = *reinterpret_cast<const float2*>(&vx0[c * PAD + r0]);
                const float2 a1 = *reinterpret_cast<const float2*>(&vx1[c * PAD + r0]);
                const float2 aq = *reinterpret_cast<const float2*>(&vq [c * PAD + r0]);
                #pragma unroll
                for (int j = 0; j < 8; ++j) {
                    const float* wp = W + ((o0 + j) * CH + c) * 3;
                    const float w0 = wp[0], w1 = wp[1], w2 = wp[2];
                    acc[0][j] += a0.x * w0 + a1.x * w1 + aq.x * w2;
                    acc[1][j] += a0.y * w0 + a1.y * w1 + aq.y * w2;
                }
            }
            __syncthreads();  // all reads of vq done before overwrite

            if (l < 2) {
                // relu, write next-layer q back into LDS ([o] becomes next [c])
                #pragma unroll
                for (int j = 0; j < 8; ++j) {
                    vq[(o0 + j) * PAD + r0 + 0] = fmaxf(acc[0][j], 0.f);
                    vq[(o0 + j) * PAD + r0 + 1] = fmaxf(acc[1][j], 0.f);
                }
                __syncthreads();
            } else {
                // epilogue: residual with ORIGINAL q, relu, store
                #pragma unroll
                for (int j = 0; j < 8; ++j) {
                    #pragma unroll
                    for (int i = 0; i < 2; ++i) {
                        const int idx = ((n0 + r0 + i) * CH + (o0 + j)) * 3 + g;
                        out[idx] = fmaxf(acc[i][j] + q[idx], 0.f);
                    }
                }
            }
        }
    }
}

extern "C" void kernel_launch(void* const* d_in, const int* in_sizes, int n_in,
                              void* d_out, int out_size, void* d_ws, size_t ws_size,
                              hipStream_t stream)
{
    const float* x  = (const float*)d_in[0];
    const float* q  = (const float*)d_in[1];
    const float* W1 = (const float*)d_in[2];
    const float* b1 = (const float*)d_in[3];
    const float* W2 = (const float*)d_in[4];
    const float* b2 = (const float*)d_in[5];
    const float* W3 = (const float*)d_in[6];
    const float* b3 = (const float*)d_in[7];
    float* out = (float*)d_out;

    dim3 grid(NROWS / TM), block(256);
    hipLaunchKernelGGL(qjrb_fused, grid, block, 0, stream,
                       x, q, W1, b1, W2, b2, W3, b3, out);
}